// Round 1
// baseline (645.746 us; speedup 1.0000x reference)
//
#include <hip/hip_runtime.h>

// ---------------------------------------------------------------------------
// CConv: out[n,o] = sum_{m,s,i} sel[n,m,s] * W[s,o,i] * feat[idx[n,m], i]
// Phase 1 (per-n mini-GEMM, 32x32x16 bf16 MFMA):  t[n,s,i] = sum_m sel*pf
// Phase 2 (big GEMM, 16x16x32 bf16 MFMA):         out = T[N,3456] x Wf[3456,128]
// T staged as bf16 in d_ws (chunked if ws is small). W pre-transposed to bf16.
// ---------------------------------------------------------------------------

#define N_CHI 128
#define N_SP  27
#define N_M   32
#define KDIM  (N_SP * N_CHI)      // 3456
#define SEL_STRIDE (N_M * N_SP)   // 864

typedef short s16x8 __attribute__((ext_vector_type(8)));
typedef s16x8 __attribute__((may_alias)) s16x8_a;
typedef unsigned short u16x8 __attribute__((ext_vector_type(8)));
typedef u16x8 __attribute__((may_alias)) u16x8_a;
typedef unsigned int u32x2 __attribute__((ext_vector_type(2)));
typedef u32x2 __attribute__((may_alias)) u32x2_a;
typedef float f32x4 __attribute__((ext_vector_type(4)));
typedef float f32x16 __attribute__((ext_vector_type(16)));

static __device__ __forceinline__ unsigned short f2bf(float f) {
  unsigned int u = __float_as_uint(f);
  u += 0x7FFFu + ((u >> 16) & 1u);   // round-to-nearest-even (inputs finite)
  return (unsigned short)(u >> 16);
}

// --------------------------------------------------------------------------
// Kernel 0: W [27][128o*128i] fp32  ->  Wt [o][s*128+i] bf16  (k contiguous)
// --------------------------------------------------------------------------
__global__ __launch_bounds__(128) void wconv_kernel(const float* __restrict__ w,
                                                    unsigned short* __restrict__ Wt) {
  const int s = blockIdx.x;    // 27
  const int o = blockIdx.y;    // 128
  const int i = threadIdx.x;   // 128
  Wt[((size_t)o * N_SP + s) * N_CHI + i] = f2bf(w[((size_t)s * 128 + o) * N_CHI + i]);
}

// --------------------------------------------------------------------------
// Kernel 1: per-n  t^T[i][s] = pf^T(128x32m) x sel(32m x 32s)  via 32x32x16
//   A[row=lane&31=i][k=(lane>>5)*8+j] gathered straight from feat (global)
//   B[k][col=lane&31=s] from LDS sel^T (bf16, row stride 40 u16 = 80B)
//   C: col=lane&31 (s), row=(reg&3)+8*(reg>>2)+4*(lane>>5) (i) -> 4 consecutive
//      i per reg-group -> packed 8B global stores of bf16 T[n][s][i]
// --------------------------------------------------------------------------
__global__ __launch_bounds__(256) void phase1_kernel(
    const float* __restrict__ feat, const float* __restrict__ sel,
    const int* __restrict__ nidx, unsigned short* __restrict__ T,
    int nbase, int nend) {
  __shared__ __align__(16) unsigned short selT[4][32 * 40];  // per-wave region
  const int wave = threadIdx.x >> 6;
  const int lane = threadIdx.x & 63;
  const int n = nbase + (int)blockIdx.x * 4 + wave;
  if (n >= nend) return;                 // wave-private LDS: no barriers needed
  unsigned short* st = selT[wave];

  // stage sel^T [s][m] bf16, s padded 27->32 with zeros
  const float* selp = sel + (size_t)n * SEL_STRIDE;
#pragma unroll
  for (int it = 0; it < 16; ++it) {
    int e = it * 64 + lane;
    int m = e >> 5, s = e & 31;
    float v = (s < N_SP) ? selp[m * N_SP + s] : 0.0f;
    st[s * 40 + m] = f2bf(v);
  }

  const int q = lane >> 5;     // 0..1  (K-half)
  const int col = lane & 31;   // A-row (i_local) == B-col (s)

  // neighbor rows for this lane's k positions: m = ks*16 + q*8 + j
  const int* ip = nidx + (size_t)n * N_M;
  int rows[16];
#pragma unroll
  for (int ks = 0; ks < 2; ++ks)
#pragma unroll
    for (int j = 0; j < 8; ++j) rows[ks * 8 + j] = ip[ks * 16 + q * 8 + j];

  // B fragments (shared across the 4 i-tiles)
  const s16x8 bf0 = *(const s16x8_a*)&st[col * 40 + q * 8];        // m = q*8+j
  const s16x8 bf1 = *(const s16x8_a*)&st[col * 40 + 16 + q * 8];   // m = 16+q*8+j

  unsigned short* Tn = T + (size_t)(n - nbase) * KDIM;
#pragma unroll
  for (int ti = 0; ti < 4; ++ti) {
    const int icol = ti * 32 + col;
    float fv[16];
#pragma unroll
    for (int t = 0; t < 16; ++t) fv[t] = feat[(size_t)rows[t] * N_CHI + icol];
    s16x8 af0, af1;
#pragma unroll
    for (int j = 0; j < 8; ++j) {
      af0[j] = (short)f2bf(fv[j]);
      af1[j] = (short)f2bf(fv[8 + j]);
    }
    f32x16 acc = {0.f, 0.f, 0.f, 0.f, 0.f, 0.f, 0.f, 0.f,
                  0.f, 0.f, 0.f, 0.f, 0.f, 0.f, 0.f, 0.f};
    acc = __builtin_amdgcn_mfma_f32_32x32x16_bf16(af0, bf0, acc, 0, 0, 0);
    acc = __builtin_amdgcn_mfma_f32_32x32x16_bf16(af1, bf1, acc, 0, 0, 0);
    if (col < N_SP) {  // s = col; drop the padding rows
      unsigned short* dst = Tn + (size_t)col * N_CHI + ti * 32 + q * 4;
#pragma unroll
      for (int g = 0; g < 4; ++g) {  // i = ti*32 + q*4 + g*8 + {0..3}
        u32x2 pk;
        pk[0] = (unsigned int)f2bf(acc[4 * g + 0]) | ((unsigned int)f2bf(acc[4 * g + 1]) << 16);
        pk[1] = (unsigned int)f2bf(acc[4 * g + 2]) | ((unsigned int)f2bf(acc[4 * g + 3]) << 16);
        *(u32x2_a*)(dst + g * 8) = pk;
      }
    }
  }
}

// --------------------------------------------------------------------------
// Kernel 2: out[64n x 128o] += T[64 x 3456] x Wt^T, 16x16x32 bf16, BK=64.
// XOR-swizzled LDS (16B blocks, b' = b ^ (row&7)) -> conflict-free b128 reads.
// 4 waves: wave (wm=w&1, wn=w>>1) owns a 32n x 64o quadrant (2x4 C-tiles).
// --------------------------------------------------------------------------
__global__ __launch_bounds__(256) void phase2_kernel(
    const unsigned short* __restrict__ T, const unsigned short* __restrict__ Wt,
    float* __restrict__ out, int nbase, int N) {
  __shared__ __align__(16) unsigned short Alds[64 * 64];    // 8 KB
  __shared__ __align__(16) unsigned short Blds[128 * 64];   // 16 KB
  const int tid = threadIdx.x;
  const int wave = tid >> 6, lane = tid & 63;
  const int wm = wave & 1, wn = wave >> 1;
  const int quad = lane >> 4, l16 = lane & 15;
  const size_t rowbase = (size_t)blockIdx.x * 64;

  f32x4 acc[2][4];
#pragma unroll
  for (int a = 0; a < 2; ++a)
#pragma unroll
    for (int b = 0; b < 4; ++b) acc[a][b] = (f32x4){0.f, 0.f, 0.f, 0.f};

  for (int kt = 0; kt < KDIM / 64; ++kt) {
    const int k0 = kt * 64;
#pragma unroll
    for (int rnd = 0; rnd < 2; ++rnd) {  // A-tile: 64 rows x 64 k
      int slot = rnd * 256 + tid;
      int m = slot >> 3, b = slot & 7;
      const u16x8_a* src =
          (const u16x8_a*)(T + (rowbase + m) * KDIM + k0 + ((b ^ (m & 7)) << 3));
      *(u16x8_a*)&Alds[slot * 8] = *src;
    }
#pragma unroll
    for (int rnd = 0; rnd < 4; ++rnd) {  // B-tile: 128 o-rows x 64 k
      int slot = rnd * 256 + tid;
      int o = slot >> 3, b = slot & 7;
      const u16x8_a* src =
          (const u16x8_a*)(Wt + (size_t)o * KDIM + k0 + ((b ^ (o & 7)) << 3));
      *(u16x8_a*)&Blds[slot * 8] = *src;
    }
    __syncthreads();
#pragma unroll
    for (int ks = 0; ks < 2; ++ks) {
      const int bg = ks * 4 + quad;  // k-block 0..7 inside BK=64
      s16x8 af[2], bfr[4];
#pragma unroll
      for (int mt = 0; mt < 2; ++mt) {
        int m = wm * 32 + mt * 16 + l16;
        af[mt] = *(const s16x8_a*)&Alds[m * 64 + ((bg ^ (m & 7)) << 3)];
      }
#pragma unroll
      for (int nt = 0; nt < 4; ++nt) {
        int o = wn * 64 + nt * 16 + l16;
        bfr[nt] = *(const s16x8_a*)&Blds[o * 64 + ((bg ^ (o & 7)) << 3)];
      }
#pragma unroll
      for (int mt = 0; mt < 2; ++mt)
#pragma unroll
        for (int nt = 0; nt < 4; ++nt)
          acc[mt][nt] = __builtin_amdgcn_mfma_f32_16x16x32_bf16(af[mt], bfr[nt],
                                                                acc[mt][nt], 0, 0, 0);
    }
    __syncthreads();
  }

#pragma unroll
  for (int mt = 0; mt < 2; ++mt) {
    const int growb = nbase + (int)rowbase + wm * 32 + mt * 16 + quad * 4;
#pragma unroll
    for (int r = 0; r < 4; ++r) {
      const int grow = growb + r;
      if (grow < N) {
#pragma unroll
        for (int nt = 0; nt < 4; ++nt) {
          const int o = wn * 64 + nt * 16 + l16;
          out[(size_t)grow * 128 + o] = acc[mt][nt][r];
        }
      }
    }
  }
}

// --------------------------------------------------------------------------
extern "C" void kernel_launch(void* const* d_in, const int* in_sizes, int n_in,
                              void* d_out, int out_size, void* d_ws, size_t ws_size,
                              hipStream_t stream) {
  const float* feat = (const float*)d_in[0];   // [N,128] fp32
  const float* sel  = (const float*)d_in[1];   // [N,32,27] fp32
  const float* wgt  = (const float*)d_in[2];   // [27,128*128] fp32
  const int*   nidx = (const int*)d_in[3];     // [N,32] int32
  float* out = (float*)d_out;                  // [N,128,1] fp32
  const int N = in_sizes[0] / N_CHI;           // 50000

  unsigned short* Wt = (unsigned short*)d_ws;        // 128*3456 bf16 = 884736 B
  const size_t WT_ELEMS = (size_t)128 * KDIM;
  unsigned short* T = Wt + WT_ELEMS;                 // chunked [NC,3456] bf16

  wconv_kernel<<<dim3(N_SP, 128), 128, 0, stream>>>(wgt, Wt);

  const size_t bytes_for_T = (ws_size > WT_ELEMS * 2) ? (ws_size - WT_ELEMS * 2) : 0;
  long cap_rows = (long)(bytes_for_T / ((size_t)KDIM * 2));
  long NC = (cap_rows / 64) * 64;
  const long Nfull = (((long)N + 63) / 64) * 64;
  if (NC > Nfull) NC = Nfull;
  if (NC <= 0) return;  // workspace too small (not expected)

  for (long nb = 0; nb < N; nb += NC) {
    long rows = (long)N - nb;
    if (rows > NC) rows = NC;
    const long rows64 = ((rows + 63) / 64) * 64;  // <= NC (NC is 64-multiple)
    phase1_kernel<<<dim3((unsigned)((rows + 3) / 4)), 256, 0, stream>>>(
        feat, sel, nidx, T, (int)nb, (int)(nb + rows));
    phase2_kernel<<<dim3((unsigned)(rows64 / 64)), 256, 0, stream>>>(
        T, Wt, out, (int)nb, N);
  }
}

// Round 2
// 545.722 us; speedup vs baseline: 1.1833x; 1.1833x over previous
//
#include <hip/hip_runtime.h>

// ---------------------------------------------------------------------------
// CConv: out[n,o] = sum_{m,s,i} sel[n,m,s] * W[s,o,i] * feat[idx[n,m], i]
// Phase 1: t[n,s,i] = sum_m sel*pf (per-n 32x32x16 MFMA), T stored via LDS
//          transpose -> coalesced 1KB stores (R1 was 8B-scatter write-bound).
// Phase 2: out = T[N,3456] x Wt^T, m97-style 128x128 tile, BK=64,
//          global_load_lds(16B) staging with global-side XOR swizzle.
// ---------------------------------------------------------------------------

#define N_CHI 128
#define N_SP  27
#define N_M   32
#define KDIM  (N_SP * N_CHI)      // 3456
#define SEL_STRIDE (N_M * N_SP)   // 864

typedef short s16x8 __attribute__((ext_vector_type(8)));
typedef s16x8 __attribute__((may_alias)) s16x8_a;
typedef unsigned short u16x8 __attribute__((ext_vector_type(8)));
typedef u16x8 __attribute__((may_alias)) u16x8_a;
typedef unsigned int u32x2 __attribute__((ext_vector_type(2)));
typedef u32x2 __attribute__((may_alias)) u32x2_a;
typedef float f32x4 __attribute__((ext_vector_type(4)));
typedef float f32x16 __attribute__((ext_vector_type(16)));

typedef __attribute__((address_space(3))) unsigned int as3_u32;
typedef __attribute__((address_space(1))) const unsigned int as1_u32;

static __device__ __forceinline__ unsigned short f2bf(float f) {
  unsigned int u = __float_as_uint(f);
  u += 0x7FFFu + ((u >> 16) & 1u);   // round-to-nearest-even (inputs finite)
  return (unsigned short)(u >> 16);
}

// --------------------------------------------------------------------------
// Kernel 0: W [27][128o*128i] fp32  ->  Wt [o][s*128+i] bf16  (k contiguous)
// --------------------------------------------------------------------------
__global__ __launch_bounds__(128) void wconv_kernel(const float* __restrict__ w,
                                                    unsigned short* __restrict__ Wt) {
  const int s = blockIdx.x;    // 27
  const int o = blockIdx.y;    // 128
  const int i = threadIdx.x;   // 128
  Wt[((size_t)o * N_SP + s) * N_CHI + i] = f2bf(w[((size_t)s * 128 + o) * N_CHI + i]);
}

// --------------------------------------------------------------------------
// Kernel 1: per-n  t^T[i][s] = pf^T(128x32m) x sel(32m x 32s)  via 32x32x16.
// acc -> per-wave LDS tbuf (8B-granule XOR swizzle: phys granule within row
// = sub ^ ((col&7)<<2)) -> 7 coalesced b128 stores of T[n][k=s*128+i].
// --------------------------------------------------------------------------
__global__ __launch_bounds__(256) void phase1_kernel(
    const float* __restrict__ feat, const float* __restrict__ sel,
    const int* __restrict__ nidx, unsigned short* __restrict__ T,
    int nbase, int nend) {
  __shared__ __align__(16) unsigned short selT[4][32 * 40];    // 10 KB
  __shared__ __align__(16) unsigned short tbuf[4][N_SP * 128]; // 27 KB
  const int wave = threadIdx.x >> 6;
  const int lane = threadIdx.x & 63;
  const int n = nbase + (int)blockIdx.x * 4 + wave;
  if (n >= nend) return;                 // wave-private LDS: no barriers needed
  unsigned short* st = selT[wave];
  unsigned short* tb = tbuf[wave];

  // stage sel^T [s][m] bf16, s padded 27->32 with zeros
  const float* selp = sel + (size_t)n * SEL_STRIDE;
#pragma unroll
  for (int it = 0; it < 16; ++it) {
    int e = it * 64 + lane;
    int m = e >> 5, s = e & 31;
    float v = (s < N_SP) ? selp[m * N_SP + s] : 0.0f;
    st[s * 40 + m] = f2bf(v);
  }

  const int q = lane >> 5;     // 0..1  (K-half)
  const int col = lane & 31;   // A-row (i_local) == B-col (s)

  // neighbor rows for this lane's k positions: m = ks*16 + q*8 + j
  const int* ip = nidx + (size_t)n * N_M;
  int rows[16];
#pragma unroll
  for (int ks = 0; ks < 2; ++ks)
#pragma unroll
    for (int j = 0; j < 8; ++j) rows[ks * 8 + j] = ip[ks * 16 + q * 8 + j];

  // B fragments (shared across the 4 i-tiles)
  const s16x8 bf0 = *(const s16x8_a*)&st[col * 40 + q * 8];        // m = q*8+j
  const s16x8 bf1 = *(const s16x8_a*)&st[col * 40 + 16 + q * 8];   // m = 16+q*8+j

#pragma unroll
  for (int ti = 0; ti < 4; ++ti) {
    const int icol = ti * 32 + col;
    float fv[16];
#pragma unroll
    for (int t = 0; t < 16; ++t) fv[t] = feat[(size_t)rows[t] * N_CHI + icol];
    s16x8 af0, af1;
#pragma unroll
    for (int j = 0; j < 8; ++j) {
      af0[j] = (short)f2bf(fv[j]);
      af1[j] = (short)f2bf(fv[8 + j]);
    }
    f32x16 acc = {0.f, 0.f, 0.f, 0.f, 0.f, 0.f, 0.f, 0.f,
                  0.f, 0.f, 0.f, 0.f, 0.f, 0.f, 0.f, 0.f};
    acc = __builtin_amdgcn_mfma_f32_32x32x16_bf16(af0, bf0, acc, 0, 0, 0);
    acc = __builtin_amdgcn_mfma_f32_32x32x16_bf16(af1, bf1, acc, 0, 0, 0);
    if (col < N_SP) {  // s = col; drop padding rows
#pragma unroll
      for (int g = 0; g < 4; ++g) {  // i = ti*32 + q*4 + g*8 + {0..3}
        const int sub = ti * 8 + g * 2 + q;                 // logical granule 0..31
        const int phys = col * 128 + (((sub ^ ((col & 7) << 2))) << 2);
        u32x2 pk;
        pk[0] = (unsigned int)f2bf(acc[4 * g + 0]) | ((unsigned int)f2bf(acc[4 * g + 1]) << 16);
        pk[1] = (unsigned int)f2bf(acc[4 * g + 2]) | ((unsigned int)f2bf(acc[4 * g + 3]) << 16);
        *(u32x2_a*)&tb[phys] = pk;
      }
    }
  }

  // coalesced store: 432 granule-pairs (16B each), 7 wave-iters
  unsigned short* Tn = T + (size_t)(n - nbase) * KDIM;
#pragma unroll
  for (int it = 0; it < 7; ++it) {
    const int P = it * 64 + lane;      // pair id, 0..431
    if (P < 432) {
      const int c = P >> 4;            // col (s), 0..26
      const int sub = (P << 1) & 31;   // even logical granule
      const int phys = c * 128 + (((sub ^ ((c & 7) << 2))) << 2);  // 16B aligned
      *(u16x8_a*)&Tn[(size_t)P * 8] = *(const u16x8_a*)&tb[phys];
    }
  }
}

// --------------------------------------------------------------------------
// Kernel 2: out[128n x 128o] = T[128 x 3456] x Wt^T, 16x16x32 bf16, BK=64.
// Staging via global_load_lds (16B/lane); XOR swizzle applied on the GLOBAL
// address (LDS side is lane-order-forced), so frag ds_read_b128 stays
// conflict-free: phys 16B-block bp holds logical bg = bp ^ (row&7).
// 4 waves: wave (wm=w&1, wn=w>>1) owns a 64n x 64o quadrant (4x4 C-tiles).
// --------------------------------------------------------------------------
__global__ __launch_bounds__(256) void phase2_kernel(
    const unsigned short* __restrict__ T, const unsigned short* __restrict__ Wt,
    float* __restrict__ out, int nbase, int N) {
  __shared__ __align__(16) unsigned short Alds[128 * 64];   // 16 KB
  __shared__ __align__(16) unsigned short Blds[128 * 64];   // 16 KB
  const int tid = threadIdx.x;
  const int lane = tid & 63;
  const int wbase = tid & ~63;          // wave*64 (uniform per wave)
  const int wave = tid >> 6;
  const int wm = wave & 1, wn = wave >> 1;
  const int quad = lane >> 4, l16 = lane & 15;
  const size_t rowbase = (size_t)blockIdx.x * 128;

  f32x4 acc[4][4];
#pragma unroll
  for (int a = 0; a < 4; ++a)
#pragma unroll
    for (int b = 0; b < 4; ++b) acc[a][b] = (f32x4){0.f, 0.f, 0.f, 0.f};

  // per-thread staging source addresses (slot = it*256 + tid -> row, 16B-block)
  const unsigned short* aga[4];
  const unsigned short* bga[4];
#pragma unroll
  for (int it = 0; it < 4; ++it) {
    const int slot = it * 256 + tid;
    const int r = slot >> 3, bp = slot & 7;
    aga[it] = T + (rowbase + r) * KDIM + ((bp ^ (r & 7)) << 3);
    bga[it] = Wt + (size_t)r * KDIM + ((bp ^ (r & 7)) << 3);
  }

  for (int kt = 0; kt < KDIM / 64; ++kt) {
    const int k0 = kt * 64;
#pragma unroll
    for (int it = 0; it < 4; ++it) {
      __builtin_amdgcn_global_load_lds(
          (as1_u32*)(const void*)(aga[it] + k0),
          (as3_u32*)(void*)&Alds[(it * 256 + wbase) * 8], 16, 0, 0);
      __builtin_amdgcn_global_load_lds(
          (as1_u32*)(const void*)(bga[it] + k0),
          (as3_u32*)(void*)&Blds[(it * 256 + wbase) * 8], 16, 0, 0);
    }
    __syncthreads();
#pragma unroll
    for (int ks = 0; ks < 2; ++ks) {
      const int bg = ks * 4 + quad;  // 16B-block 0..7 inside BK=64
      s16x8 af[4], bfr[4];
#pragma unroll
      for (int mt = 0; mt < 4; ++mt) {
        const int m = wm * 64 + mt * 16 + l16;
        af[mt] = *(const s16x8_a*)&Alds[m * 64 + ((bg ^ (m & 7)) << 3)];
      }
#pragma unroll
      for (int nt = 0; nt < 4; ++nt) {
        const int o = wn * 64 + nt * 16 + l16;
        bfr[nt] = *(const s16x8_a*)&Blds[o * 64 + ((bg ^ (o & 7)) << 3)];
      }
#pragma unroll
      for (int mt = 0; mt < 4; ++mt)
#pragma unroll
        for (int nt = 0; nt < 4; ++nt)
          acc[mt][nt] = __builtin_amdgcn_mfma_f32_16x16x32_bf16(af[mt], bfr[nt],
                                                                acc[mt][nt], 0, 0, 0);
    }
    __syncthreads();
  }

#pragma unroll
  for (int mt = 0; mt < 4; ++mt) {
    const int growb = nbase + (int)rowbase + wm * 64 + mt * 16 + quad * 4;
#pragma unroll
    for (int r = 0; r < 4; ++r) {
      const int grow = growb + r;
      if (grow < N) {
#pragma unroll
        for (int nt = 0; nt < 4; ++nt) {
          const int o = wn * 64 + nt * 16 + l16;
          out[(size_t)grow * 128 + o] = acc[mt][nt][r];
        }
      }
    }
  }
}

// --------------------------------------------------------------------------
extern "C" void kernel_launch(void* const* d_in, const int* in_sizes, int n_in,
                              void* d_out, int out_size, void* d_ws, size_t ws_size,
                              hipStream_t stream) {
  const float* feat = (const float*)d_in[0];   // [N,128] fp32
  const float* sel  = (const float*)d_in[1];   // [N,32,27] fp32
  const float* wgt  = (const float*)d_in[2];   // [27,128*128] fp32
  const int*   nidx = (const int*)d_in[3];     // [N,32] int32
  float* out = (float*)d_out;                  // [N,128,1] fp32
  const int N = in_sizes[0] / N_CHI;           // 50000

  unsigned short* Wt = (unsigned short*)d_ws;        // 128*3456 bf16 = 884736 B
  const size_t WT_ELEMS = (size_t)128 * KDIM;
  unsigned short* T = Wt + WT_ELEMS;                 // chunked [NC,3456] bf16

  wconv_kernel<<<dim3(N_SP, 128), 128, 0, stream>>>(wgt, Wt);

  const size_t bytes_for_T = (ws_size > WT_ELEMS * 2) ? (ws_size - WT_ELEMS * 2) : 0;
  long cap_rows = (long)(bytes_for_T / ((size_t)KDIM * 2));
  long NC = (cap_rows / 128) * 128;
  const long Nfull = (((long)N + 127) / 128) * 128;
  if (NC > Nfull) NC = Nfull;
  if (NC <= 0) return;  // workspace too small (not expected)

  for (long nb = 0; nb < N; nb += NC) {
    long rows = (long)N - nb;
    if (rows > NC) rows = NC;
    const long rows128 = ((rows + 127) / 128) * 128;  // <= NC
    phase1_kernel<<<dim3((unsigned)((rows + 3) / 4)), 256, 0, stream>>>(
        feat, sel, nidx, T, (int)nb, (int)(nb + rows));
    phase2_kernel<<<dim3((unsigned)(rows128 / 128)), 256, 0, stream>>>(
        T, Wt, out, (int)nb, N);
  }
}